// Round 1
// baseline (406.889 us; speedup 1.0000x reference)
//
#include <hip/hip_runtime.h>
#include <math.h>

// NoRefRetIQANet: cosine top-K retrieval.
//   score[b,n] = dot(q_b, d_n) / ||d_n||   (query norm skipped: order-invariant)
//   top-9 indices per row (desc value, asc index ties) -> gather metrics ->
//   retrieved[b][2j+m], result[b] = mean.
// d_out layout: [0,64) result, [64, 64+64*18) retrieved.
// d_ws: sem scores [64][20000] f32, then dst scores [64][20000] f32 (10.24 MB).

#define BQ   64
#define NDB  20000
#define BN   32
#define BK   32
#define KSEM 4096
#define KDST 2048
#define NT_SEM (NDB / BN)   // 625 tiles per matrix

// ---------------------------------------------------------------------------
// GEMM: one launch covers both matmuls. Block = 256 thr, tile 64q x 32n x 32k.
// Thread tile 4q x 2n. q_s row-major [64][36] (b128 reads, 2-way = free);
// d_s K-major [32][34] (float2 reads conflict-free). Double-buffered, register
// prefetch. DB row sum-of-squares accumulated during staging -> 1/||d_n||.
// ---------------------------------------------------------------------------
__global__ __launch_bounds__(256) void score_kernel(
    const float* __restrict__ fc, const float* __restrict__ fd,
    const float* __restrict__ sdb, const float* __restrict__ ddb,
    float* __restrict__ s_sem, float* __restrict__ s_dst)
{
    __shared__ float q_s[2][BQ][BK + 4];     // 18432 B
    __shared__ float d_s[2][BK][BN + 2];     //  8704 B
    __shared__ float red_s[BN][8];
    __shared__ float invn_s[BN];

    const int tid = threadIdx.x;
    const bool isSem = (int)blockIdx.x < NT_SEM;
    const float* __restrict__ Q = isSem ? fc : fd;
    const float* __restrict__ D = isSem ? sdb : ddb;
    float* __restrict__ S = isSem ? s_sem : s_dst;
    const int K  = isSem ? KSEM : KDST;
    const int n0 = (isSem ? (int)blockIdx.x : (int)blockIdx.x - NT_SEM) * BN;

    // staging map: thread -> (row sr, float4 chunk sc); stages d row sr and
    // q rows sr, sr+32 every K-step.
    const int sr = tid >> 3;                 // 0..31
    const int sc = tid & 7;                  // 0..7
    const float* dptr  = D + (size_t)(n0 + sr) * K + sc * 4;
    const float* qptr0 = Q + (size_t)sr * K + sc * 4;
    const float* qptr1 = qptr0 + (size_t)32 * K;

    // compute map: 16x16 thread grid, tile 4q x 2n
    const int ty = tid >> 4;
    const int tx = tid & 15;
    const int qb = ty * 4;
    const int nb = tx * 2;

    float acc[4][2] = {{0.f,0.f},{0.f,0.f},{0.f,0.f},{0.f,0.f}};
    float sq = 0.f;
    const int nsteps = K / BK;

    // prologue: stage step 0
    {
        float4 dv  = *(const float4*)dptr;
        float4 qv0 = *(const float4*)qptr0;
        float4 qv1 = *(const float4*)qptr1;
        sq += dv.x*dv.x + dv.y*dv.y + dv.z*dv.z + dv.w*dv.w;
        d_s[0][sc*4+0][sr] = dv.x;
        d_s[0][sc*4+1][sr] = dv.y;
        d_s[0][sc*4+2][sr] = dv.z;
        d_s[0][sc*4+3][sr] = dv.w;
        *(float4*)&q_s[0][sr][sc*4]      = qv0;
        *(float4*)&q_s[0][sr+32][sc*4]   = qv1;
    }
    __syncthreads();

    int cur = 0;
    for (int t = 0; t < nsteps; ++t) {
        const bool more = (t + 1) < nsteps;
        float4 dvn, qv0n, qv1n;
        if (more) {                          // prefetch next tile into regs
            const int off = (t + 1) * BK;
            dvn  = *(const float4*)(dptr  + off);
            qv0n = *(const float4*)(qptr0 + off);
            qv1n = *(const float4*)(qptr1 + off);
        }
        // compute current buffer: 256 FMAs/thread hides prefetch latency
        #pragma unroll
        for (int kk = 0; kk < BK; kk += 4) {
            float4 a[4];
            #pragma unroll
            for (int i = 0; i < 4; ++i)
                a[i] = *(const float4*)&q_s[cur][qb + i][kk];
            #pragma unroll
            for (int u = 0; u < 4; ++u) {
                float2 bv = *(const float2*)&d_s[cur][kk + u][nb];
                #pragma unroll
                for (int i = 0; i < 4; ++i) {
                    const float av = (u == 0) ? a[i].x : (u == 1) ? a[i].y
                                   : (u == 2) ? a[i].z : a[i].w;
                    acc[i][0] = fmaf(av, bv.x, acc[i][0]);
                    acc[i][1] = fmaf(av, bv.y, acc[i][1]);
                }
            }
        }
        if (more) {
            sq += dvn.x*dvn.x + dvn.y*dvn.y + dvn.z*dvn.z + dvn.w*dvn.w;
            const int nxt = cur ^ 1;
            d_s[nxt][sc*4+0][sr] = dvn.x;
            d_s[nxt][sc*4+1][sr] = dvn.y;
            d_s[nxt][sc*4+2][sr] = dvn.z;
            d_s[nxt][sc*4+3][sr] = dvn.w;
            *(float4*)&q_s[nxt][sr][sc*4]    = qv0n;
            *(float4*)&q_s[nxt][sr+32][sc*4] = qv1n;
        }
        __syncthreads();
        cur ^= 1;
    }

    // row inverse norms: reduce the 8 chunk-partials per row
    red_s[sr][sc] = sq;
    __syncthreads();
    if (tid < BN) {
        float s = 0.f;
        #pragma unroll
        for (int c = 0; c < 8; ++c) s += red_s[tid][c];
        invn_s[tid] = 1.0f / sqrtf(s);
    }
    __syncthreads();

    const float i0 = invn_s[nb], i1 = invn_s[nb + 1];
    #pragma unroll
    for (int i = 0; i < 4; ++i) {
        float2 o;
        o.x = acc[i][0] * i0;
        o.y = acc[i][1] * i1;
        *(float2*)(S + (size_t)(qb + i) * NDB + n0 + nb) = o;
    }
}

// ---------------------------------------------------------------------------
// Top-9 per (matrix m, row b): per-thread streaming top-9 over 20000/256
// elements, then LDS tree merge. Comparator: value desc, index asc on ties
// (matches lax.top_k). Writes metrics[idx] into retrieved[b][2j+m].
// ---------------------------------------------------------------------------
__global__ __launch_bounds__(256) void topk_kernel(
    const float* __restrict__ s_sem, const float* __restrict__ s_dst,
    const float* __restrict__ metrics, float* __restrict__ out_ret)
{
    __shared__ float sv[256][9];
    __shared__ int   si[256][9];

    const int tid = threadIdx.x;
    const int b = (int)blockIdx.x & 63;
    const int m = (int)blockIdx.x >> 6;      // 0=sem, 1=dst
    const float* __restrict__ row = (m == 0 ? s_sem : s_dst) + (size_t)b * NDB;

    // local top-9, ascending (v[0] weakest). All indexing compile-time static.
    float v[9]; int ix[9];
    #pragma unroll
    for (int k = 0; k < 9; ++k) { v[k] = -INFINITY; ix[k] = 0x7fffffff; }

    for (int i = tid; i < NDB; i += 256) {
        const float sval = row[i];
        if (sval > v[0]) {                   // equal value never beats (lower idx already held)
            bool bt[9];
            bt[0] = true;
            #pragma unroll
            for (int j = 1; j < 9; ++j) bt[j] = sval > v[j];
            #pragma unroll
            for (int j = 0; j < 8; ++j) {
                v[j]  = bt[j+1] ? v[j+1]  : (bt[j] ? sval : v[j]);
                ix[j] = bt[j+1] ? ix[j+1] : (bt[j] ? i    : ix[j]);
            }
            v[8]  = bt[8] ? sval : v[8];
            ix[8] = bt[8] ? i    : ix[8];
        }
    }

    #pragma unroll
    for (int k = 0; k < 9; ++k) { sv[tid][k] = v[k]; si[tid][k] = ix[k]; }
    __syncthreads();

    // tree merge: 256 -> 1 sorted-9 lists
    for (int s2 = 128; s2 >= 1; s2 >>= 1) {
        if (tid < s2) {
            float rv[9]; int ri[9];
            int pa = 8, pb = 8;
            #pragma unroll
            for (int k = 8; k >= 0; --k) {
                const float va = sv[tid][pa];      const int ia = si[tid][pa];
                const float vb = sv[tid + s2][pb]; const int ib = si[tid + s2][pb];
                const bool takeA = (va > vb) || (va == vb && ia < ib);
                rv[k] = takeA ? va : vb;
                ri[k] = takeA ? ia : ib;
                if (takeA) --pa; else --pb;
            }
            #pragma unroll
            for (int k = 0; k < 9; ++k) { sv[tid][k] = rv[k]; si[tid][k] = ri[k]; }
        }
        __syncthreads();
    }

    if (tid < 9) {
        const int idx = si[0][8 - tid];          // descending order j = tid
        out_ret[(size_t)b * 18 + 2 * tid + m] = metrics[idx];
    }
}

// result[b] = mean(retrieved[b][0..17])
__global__ void finalize_kernel(float* __restrict__ d_out)
{
    const int b = threadIdx.x;
    const float* r = d_out + 64 + (size_t)b * 18;
    float s = 0.f;
    #pragma unroll
    for (int j = 0; j < 18; ++j) s += r[j];
    d_out[b] = s * (1.0f / 18.0f);
}

extern "C" void kernel_launch(void* const* d_in, const int* in_sizes, int n_in,
                              void* d_out, int out_size, void* d_ws, size_t ws_size,
                              hipStream_t stream)
{
    const float* fc  = (const float*)d_in[0];   // [64][4096]
    const float* fd  = (const float*)d_in[1];   // [64][2048]
    const float* sdb = (const float*)d_in[2];   // [20000][4096]
    const float* ddb = (const float*)d_in[3];   // [20000][2048]
    const float* met = (const float*)d_in[4];   // [20000]

    float* s_sem = (float*)d_ws;
    float* s_dst = s_sem + (size_t)BQ * NDB;
    float* out   = (float*)d_out;

    score_kernel<<<dim3(NT_SEM * 2), dim3(256), 0, stream>>>(
        fc, fd, sdb, ddb, s_sem, s_dst);
    topk_kernel<<<dim3(128), dim3(256), 0, stream>>>(
        s_sem, s_dst, met, out + 64);
    finalize_kernel<<<dim3(1), dim3(64), 0, stream>>>(out);
}

// Round 2
// 216.969 us; speedup vs baseline: 1.8753x; 1.8753x over previous
//
#include <hip/hip_runtime.h>
#include <math.h>

// NoRefRetIQANet: cosine top-K retrieval via fp16 2-split MFMA.
//   score[b,n] = dot(q_b, d_n) / ||d_n||  (query norm skipped: order-invariant)
//   x = hi + lo/4096 exactly to ~2^-24 rel;  dot = hh + (hl + lh)/4096
//   (f16*f16 exact in f32 accumulate; dropped ll term ~2^-24 -> fp32-level noise)
// ws layout: semp0[64][20000] f32, semp1, dstp, nsq0[20000], nsq1, nsqd,
//            qc_hi[64][4096] f16, qc_lo, qd_hi[64][2048], qd_lo  (~17.2 MB)
// d_out: [0,64) result, [64, 64+64*18) retrieved.

typedef _Float16 half8  __attribute__((ext_vector_type(8)));
typedef _Float16 half4v __attribute__((ext_vector_type(4)));
typedef float    f32x4  __attribute__((ext_vector_type(4)));

#define NDB   20000
#define NQ    64
#define KSEM  4096
#define KDST  2048
#define KC    2048          // uniform K-chunk per block
#define NSTEP (KC / 32)     // 64 K-steps of 32
#define NTILE 313           // ceil(20000/64)
#define BN    64

// ---------------------------------------------------------------------------
// Split queries fp32 -> (hi, lo*4096) fp16 pairs, row-major k-contiguous.
// ---------------------------------------------------------------------------
__global__ __launch_bounds__(256) void qsplit_kernel(
    const float* __restrict__ fc, const float* __restrict__ fd,
    _Float16* __restrict__ qc_hi, _Float16* __restrict__ qc_lo,
    _Float16* __restrict__ qd_hi, _Float16* __restrict__ qd_lo)
{
    const int idx = (int)blockIdx.x * 256 + (int)threadIdx.x;  // float4 idx
    const int NC4 = NQ * KSEM / 4;                             // 65536
    const float* src; _Float16 *dh, *dl; int p;
    if (idx < NC4) { src = fc; dh = qc_hi; dl = qc_lo; p = idx; }
    else           { src = fd; dh = qd_hi; dl = qd_lo; p = idx - NC4; }
    const float4 v = ((const float4*)src)[p];
    const float xs[4] = {v.x, v.y, v.z, v.w};
    half4v hi, lo;
    #pragma unroll
    for (int e = 0; e < 4; ++e) {
        const _Float16 h = (_Float16)xs[e];
        const float hf = (float)h;                 // exact
        const _Float16 l = (_Float16)((xs[e] - hf) * 4096.0f);  // sub exact (Sterbenz)
        hi[e] = h; lo[e] = l;
    }
    ((half4v*)dh)[p] = hi;
    ((half4v*)dl)[p] = lo;
}

// ---------------------------------------------------------------------------
// GEMM: 939 uniform blocks = 313 n-tiles x {sem kc0, sem kc1, dst}.
// Block: 128 thr / 2 waves, tile 64q x 64n x (KC=2048). Wave tile 64x32.
// LDS: A,B fp16 hi/lo double-buffered, 40-halves padded rows (2-way max).
// DB f32 staged via regs with inline hi/lo split; row sum-sq -> norm partials.
// MFMA 16x16x32 f16; frags: lane l reads [row=(l&15)+16i][k0=(l>>4)*8] (m97).
// ---------------------------------------------------------------------------
__global__ __launch_bounds__(128, 2) void score_kernel(
    const float* __restrict__ sdb, const float* __restrict__ ddb,
    const _Float16* __restrict__ qc_hi, const _Float16* __restrict__ qc_lo,
    const _Float16* __restrict__ qd_hi, const _Float16* __restrict__ qd_lo,
    float* __restrict__ semp0, float* __restrict__ semp1, float* __restrict__ dstp,
    float* __restrict__ nsq0, float* __restrict__ nsq1, float* __restrict__ nsqd)
{
    __shared__ __align__(16) _Float16 A_lds[2][2][64][40];  // [buf][split][row][k]
    __shared__ __align__(16) _Float16 B_lds[2][2][64][40];  // [buf][split][col][k]

    const int tid = threadIdx.x;
    const int bid = blockIdx.x;
    const int mkc = bid / NTILE;          // 0: sem kc0, 1: sem kc1, 2: dst
    const int nt  = bid % NTILE;
    const int n0  = nt * BN;

    const float* D; const _Float16 *Qh, *Ql; float *SOUT, *NOUT; int Ks, koff;
    if (mkc == 0)      { D=sdb; Qh=qc_hi; Ql=qc_lo; SOUT=semp0; NOUT=nsq0; Ks=KSEM; koff=0;  }
    else if (mkc == 1) { D=sdb; Qh=qc_hi; Ql=qc_lo; SOUT=semp1; NOUT=nsq1; Ks=KSEM; koff=KC; }
    else               { D=ddb; Qh=qd_hi; Ql=qd_lo; SOUT=dstp;  NOUT=nsqd; Ks=KDST; koff=0;  }

    // staging map: thread -> (row r 0..63, half h 0..1 of 32-k step)
    const int r = tid >> 1;
    const int h = tid & 1;
    const int nrow  = n0 + r;
    const int nclmp = nrow < NDB ? nrow : NDB - 1;
    const float*    bsrc   = D  + (size_t)nclmp * Ks + koff + h * 16;
    const _Float16* ah_src = Qh + (size_t)r * Ks + koff + h * 16;
    const _Float16* al_src = Ql + (size_t)r * Ks + koff + h * 16;

    // compute map
    const int l  = tid & 63;
    const int w  = tid >> 6;              // wave: n-cols [w*32, w*32+32)
    const int lr = l & 15;
    const int kg = l >> 4;
    const int k0 = kg * 8;

    f32x4 acc_h[4][2], acc_x[4][2];
    const f32x4 zz = {0.f, 0.f, 0.f, 0.f};
    #pragma unroll
    for (int i = 0; i < 4; ++i)
        #pragma unroll
        for (int j = 0; j < 2; ++j) { acc_h[i][j] = zz; acc_x[i][j] = zz; }

    float sq = 0.f;

    auto stage_regs = [&](int step, float4* b4, uint4* a4) {
        const float* bp = bsrc + (size_t)step * 32;
        #pragma unroll
        for (int c = 0; c < 4; ++c) b4[c] = ((const float4*)bp)[c];
        const _Float16* ap0 = ah_src + (size_t)step * 32;
        const _Float16* ap1 = al_src + (size_t)step * 32;
        a4[0] = ((const uint4*)ap0)[0]; a4[1] = ((const uint4*)ap0)[1];
        a4[2] = ((const uint4*)ap1)[0]; a4[3] = ((const uint4*)ap1)[1];
    };

    auto convert_write = [&](int buf, const float4* b4, const uint4* a4) {
        half8 bh[2], bl[2];
        float sadd = 0.f;
        #pragma unroll
        for (int c = 0; c < 4; ++c) {
            const float xs[4] = {b4[c].x, b4[c].y, b4[c].z, b4[c].w};
            #pragma unroll
            for (int e = 0; e < 4; ++e) {
                const float x = xs[e];
                sadd = fmaf(x, x, sadd);
                const _Float16 hi = (_Float16)x;
                const float hf = (float)hi;
                const _Float16 lo = (_Float16)((x - hf) * 4096.0f);
                const int ei = c * 4 + e;
                bh[ei >> 3][ei & 7] = hi;
                bl[ei >> 3][ei & 7] = lo;
            }
        }
        sq += sadd;
        *(half8*)&B_lds[buf][0][r][h*16]     = bh[0];
        *(half8*)&B_lds[buf][0][r][h*16 + 8] = bh[1];
        *(half8*)&B_lds[buf][1][r][h*16]     = bl[0];
        *(half8*)&B_lds[buf][1][r][h*16 + 8] = bl[1];
        *(uint4*)&A_lds[buf][0][r][h*16]     = a4[0];
        *(uint4*)&A_lds[buf][0][r][h*16 + 8] = a4[1];
        *(uint4*)&A_lds[buf][1][r][h*16]     = a4[2];
        *(uint4*)&A_lds[buf][1][r][h*16 + 8] = a4[3];
    };

    auto compute = [&](int buf) {
        half8 bhf[2], blf[2];
        #pragma unroll
        for (int j = 0; j < 2; ++j) {
            const int col = w*32 + j*16 + lr;
            bhf[j] = *(const half8*)&B_lds[buf][0][col][k0];
            blf[j] = *(const half8*)&B_lds[buf][1][col][k0];
        }
        #pragma unroll
        for (int i = 0; i < 4; ++i) {
            const int row = i*16 + lr;
            const half8 ah = *(const half8*)&A_lds[buf][0][row][k0];
            const half8 al = *(const half8*)&A_lds[buf][1][row][k0];
            #pragma unroll
            for (int j = 0; j < 2; ++j) {
                acc_h[i][j] = __builtin_amdgcn_mfma_f32_16x16x32_f16(ah, bhf[j], acc_h[i][j], 0, 0, 0);
                acc_x[i][j] = __builtin_amdgcn_mfma_f32_16x16x32_f16(ah, blf[j], acc_x[i][j], 0, 0, 0);
                acc_x[i][j] = __builtin_amdgcn_mfma_f32_16x16x32_f16(al, bhf[j], acc_x[i][j], 0, 0, 0);
            }
        }
    };

    {   // prologue
        float4 b4[4]; uint4 a4[4];
        stage_regs(0, b4, a4);
        convert_write(0, b4, a4);
    }
    __syncthreads();

    int cur = 0;
    for (int s = 0; s < NSTEP; ++s) {
        float4 b4n[4]; uint4 a4n[4];
        const bool more = (s + 1) < NSTEP;
        if (more) stage_regs(s + 1, b4n, a4n);   // global loads in flight
        compute(cur);                            // MFMA hides load latency
        if (more) convert_write(cur ^ 1, b4n, a4n);
        __syncthreads();                         // one barrier/iter suffices
        cur ^= 1;
    }

    // norm partials: pair (h=0,h=1) covers a full row's chunk
    const float sq2 = sq + __shfl_xor(sq, 1);
    if (h == 0 && nrow < NDB) NOUT[nrow] = sq2;

    // scores: C/D map col=lane&15, row=(lane>>4)*4+reg (m89-verified)
    #pragma unroll
    for (int j = 0; j < 2; ++j) {
        const int n = n0 + w*32 + j*16 + lr;
        if (n < NDB) {
            #pragma unroll
            for (int i = 0; i < 4; ++i) {
                #pragma unroll
                for (int rr = 0; rr < 4; ++rr) {
                    const int q = i*16 + kg*4 + rr;
                    SOUT[(size_t)q * NDB + n] =
                        acc_h[i][j][rr] + acc_x[i][j][rr] * (1.0f / 4096.0f);
                }
            }
        }
    }
}

// ---------------------------------------------------------------------------
// Top-9 per (matrix m, row b); combines sem partials and applies 1/||d_n||.
// Comparator: value desc, index asc (matches lax.top_k).
// ---------------------------------------------------------------------------
__global__ __launch_bounds__(256) void topk_kernel(
    const float* __restrict__ semp0, const float* __restrict__ semp1,
    const float* __restrict__ dstp,
    const float* __restrict__ nsq0, const float* __restrict__ nsq1,
    const float* __restrict__ nsqd,
    const float* __restrict__ metrics, float* __restrict__ out_ret)
{
    __shared__ float sv[256][9];
    __shared__ int   si[256][9];

    const int tid = threadIdx.x;
    const int b = (int)blockIdx.x & 63;
    const int m = (int)blockIdx.x >> 6;   // 0=sem, 1=dst

    float v[9]; int ix[9];
    #pragma unroll
    for (int k = 0; k < 9; ++k) { v[k] = -INFINITY; ix[k] = 0x7fffffff; }

    const size_t roff = (size_t)b * NDB;
    for (int i = tid; i < NDB; i += 256) {
        float sval;
        if (m == 0) {
            const float s = semp0[roff + i] + semp1[roff + i];
            sval = s * (1.0f / sqrtf(nsq0[i] + nsq1[i]));
        } else {
            sval = dstp[roff + i] * (1.0f / sqrtf(nsqd[i]));
        }
        if (sval > v[0]) {
            bool bt[9];
            bt[0] = true;
            #pragma unroll
            for (int j = 1; j < 9; ++j) bt[j] = sval > v[j];
            #pragma unroll
            for (int j = 0; j < 8; ++j) {
                v[j]  = bt[j+1] ? v[j+1]  : (bt[j] ? sval : v[j]);
                ix[j] = bt[j+1] ? ix[j+1] : (bt[j] ? i    : ix[j]);
            }
            v[8]  = bt[8] ? sval : v[8];
            ix[8] = bt[8] ? i    : ix[8];
        }
    }

    #pragma unroll
    for (int k = 0; k < 9; ++k) { sv[tid][k] = v[k]; si[tid][k] = ix[k]; }
    __syncthreads();

    for (int s2 = 128; s2 >= 1; s2 >>= 1) {
        if (tid < s2) {
            float rv[9]; int ri[9];
            int pa = 8, pb = 8;
            #pragma unroll
            for (int k = 8; k >= 0; --k) {
                const float va = sv[tid][pa];      const int ia = si[tid][pa];
                const float vb = sv[tid + s2][pb]; const int ib = si[tid + s2][pb];
                const bool takeA = (va > vb) || (va == vb && ia < ib);
                rv[k] = takeA ? va : vb;
                ri[k] = takeA ? ia : ib;
                if (takeA) --pa; else --pb;
            }
            #pragma unroll
            for (int k = 0; k < 9; ++k) { sv[tid][k] = rv[k]; si[tid][k] = ri[k]; }
        }
        __syncthreads();
    }

    if (tid < 9) {
        const int idx = si[0][8 - tid];
        out_ret[(size_t)b * 18 + 2 * tid + m] = metrics[idx];
    }
}

__global__ void finalize_kernel(float* __restrict__ d_out)
{
    const int b = threadIdx.x;
    const float* r = d_out + 64 + (size_t)b * 18;
    float s = 0.f;
    #pragma unroll
    for (int j = 0; j < 18; ++j) s += r[j];
    d_out[b] = s * (1.0f / 18.0f);
}

extern "C" void kernel_launch(void* const* d_in, const int* in_sizes, int n_in,
                              void* d_out, int out_size, void* d_ws, size_t ws_size,
                              hipStream_t stream)
{
    const float* fc  = (const float*)d_in[0];   // [64][4096]
    const float* fd  = (const float*)d_in[1];   // [64][2048]
    const float* sdb = (const float*)d_in[2];   // [20000][4096]
    const float* ddb = (const float*)d_in[3];   // [20000][2048]
    const float* met = (const float*)d_in[4];   // [20000]

    float* semp0 = (float*)d_ws;
    float* semp1 = semp0 + (size_t)NQ * NDB;
    float* dstp  = semp1 + (size_t)NQ * NDB;
    float* nsq0  = dstp  + (size_t)NQ * NDB;
    float* nsq1  = nsq0 + NDB;
    float* nsqd  = nsq1 + NDB;
    _Float16* qc_hi = (_Float16*)(nsqd + NDB);
    _Float16* qc_lo = qc_hi + (size_t)NQ * KSEM;
    _Float16* qd_hi = qc_lo + (size_t)NQ * KSEM;
    _Float16* qd_lo = qd_hi + (size_t)NQ * KDST;

    float* out = (float*)d_out;

    qsplit_kernel<<<dim3(384), dim3(256), 0, stream>>>(
        fc, fd, qc_hi, qc_lo, qd_hi, qd_lo);
    score_kernel<<<dim3(3 * NTILE), dim3(128), 0, stream>>>(
        sdb, ddb, qc_hi, qc_lo, qd_hi, qd_lo,
        semp0, semp1, dstp, nsq0, nsq1, nsqd);
    topk_kernel<<<dim3(128), dim3(256), 0, stream>>>(
        semp0, semp1, dstp, nsq0, nsq1, nsqd, met, out + 64);
    finalize_kernel<<<dim3(1), dim3(64), 0, stream>>>(out);
}